// Round 13
// baseline (268.478 us; speedup 1.0000x reference)
//
#include <hip/hip_runtime.h>
#include <hip/hip_fp16.h>

// Masked Sinkhorn via diagonal-scaling algebra on A = s+EPS:
//   c <- 1/(A^T r), r <- 1/(A c), out = A ∘ (r9 c8^T) on valid block.
// R13 = R11/R12 resubmitted (container infrastructure died twice before run).
// R7 6-dispatch structure (230us) + 256-col TILE SKIPPING:
// q is written/read only for tiles with tile_start < nc (avg 3.5/4 tiles),
// eliminating the zero-region traffic R10's counters exposed (~270MB of
// HBM q-miss reads came from streaming the full 1024-wide rows).
// cm masking (already present) handles the sub-tile sliver beyond nc.
// fp16 q with EPS baked in; folded c-reduce; regular float4 out stores.

namespace {
constexpr int B_ = 64;
constexpr int N_ = 1024;
constexpr int M_ = 1024;
constexpr float EPS_ = 1e-4f;
constexpr int PCHUNK = 16;        // row chunks / blocks per batch
constexpr int RPC = N_ / PCHUNK;  // 64 rows per chunk
}

typedef float f32x4_ __attribute__((ext_vector_type(4)));

__device__ __forceinline__ float4 nt_load4(const float* p) {
    f32x4_ v = __builtin_nontemporal_load(reinterpret_cast<const f32x4_*>(p));
    return float4{v.x, v.y, v.z, v.w};
}

// ---------------------------------------------------------------------------
// Prep: q = fp16(s+EPS) for valid rows, ACTIVE TILES ONLY (tile t active iff
// t*256 < nc; within an active tile, elements >= nc stored as 0), plus iter-0
// column-sum partials. grid (PCHUNK, B), block 256 = 4 waves x 16 rows.
// Lane owns cols {t*256 + lane*4 .. +3}, t = 0..3.
__global__ void prep_pass(const float* __restrict__ s,
                          __half* __restrict__ q,
                          float* __restrict__ partial,
                          const int* __restrict__ nrows,
                          const int* __restrict__ ncols) {
    __shared__ float lds[4][M_];
    const int b = blockIdx.y, p = blockIdx.x;
    const int nr = nrows[b], nc = ncols[b];
    const int wave = threadIdx.x >> 6, lane = threadIdx.x & 63;

    float4 ca[4];
#pragma unroll
    for (int t = 0; t < 4; ++t) ca[t] = float4{0.f, 0.f, 0.f, 0.f};

    const int rbeg = p * RPC + wave * 16;
    const int rend = min(rbeg + 16, nr);
    const float* sb = s + (size_t)b * N_ * M_;
    __half* qb = q + (size_t)b * N_ * M_;

    for (int n = rbeg; n < rend; ++n) {
#pragma unroll
        for (int t = 0; t < 4; ++t) {
            if (t * 256 < nc) {  // active tile (wave-uniform)
                const int m0 = t * 256 + lane * 4;
                float4 v = {0.f, 0.f, 0.f, 0.f};
                if (m0 < nc) {
                    v = nt_load4(sb + (size_t)n * M_ + m0);
                    v.x += EPS_; v.y += EPS_; v.z += EPS_; v.w += EPS_;
                }
                __half2 h01 = __floats2half2_rn(v.x, v.y);
                __half2 h23 = __floats2half2_rn(v.z, v.w);
                uint2 st;
                st.x = *reinterpret_cast<const unsigned*>(&h01);
                st.y = *reinterpret_cast<const unsigned*>(&h23);
                *reinterpret_cast<uint2*>(qb + (size_t)n * M_ + m0) = st;
                ca[t].x += v.x; ca[t].y += v.y; ca[t].z += v.z; ca[t].w += v.w;
            }
        }
    }
#pragma unroll
    for (int t = 0; t < 4; ++t)
        *reinterpret_cast<float4*>(&lds[wave][t * 256 + lane * 4]) = ca[t];
    __syncthreads();
    const int m0 = threadIdx.x * 4;
    const float4 a0 = *reinterpret_cast<const float4*>(&lds[0][m0]);
    const float4 a1 = *reinterpret_cast<const float4*>(&lds[1][m0]);
    const float4 a2 = *reinterpret_cast<const float4*>(&lds[2][m0]);
    const float4 a3 = *reinterpret_cast<const float4*>(&lds[3][m0]);
    float4 o;
    o.x = a0.x + a1.x + a2.x + a3.x;
    o.y = a0.y + a1.y + a2.y + a3.y;
    o.z = a0.z + a1.z + a2.z + a3.z;
    o.w = a0.w + a1.w + a2.w + a3.w;
    *reinterpret_cast<float4*>(partial + ((size_t)b * PCHUNK + p) * M_ + m0) = o;
}

// ---------------------------------------------------------------------------
// Dequant 4 fp16 (uint2) -> 4 fp32.
__device__ __forceinline__ void dq4(const uint2& r, float* f) {
    const float2 a = __half22float2(*reinterpret_cast<const __half2*>(&r.x));
    const float2 b = __half22float2(*reinterpret_cast<const __half2*>(&r.y));
    f[0] = a.x; f[1] = a.y; f[2] = b.x; f[3] = b.y;
}

// ---------------------------------------------------------------------------
// Fused pair: c = 1/reduce(partial_in) (folded, in LDS, identical order in
// every block); r = 1/(q c) per row; col partials of q^T r -> partial_out.
// Active-tile reads only. grid (PCHUNK, B), block 256 = 4 waves x 16 rows.
__global__ void fused_pass_h(const __half* __restrict__ q,
                             const float* __restrict__ partial_in,
                             float* __restrict__ partial_out,
                             const int* __restrict__ nrows,
                             const int* __restrict__ ncols) {
    __shared__ float lds[4][M_];
    const int b = blockIdx.y, p = blockIdx.x;
    const int nr = nrows[b], nc = ncols[b];
    const int wave = threadIdx.x >> 6, lane = threadIdx.x & 63;

    // phase 1: c = 1/colsum into lds[0][.]
    {
        const int m0 = threadIdx.x * 4;
        const float* pp = partial_in + (size_t)b * PCHUNK * M_ + m0;
        float4 sacc = {0.f, 0.f, 0.f, 0.f};
#pragma unroll
        for (int i = 0; i < PCHUNK; ++i) {
            const float4 v = *reinterpret_cast<const float4*>(pp + (size_t)i * M_);
            sacc.x += v.x; sacc.y += v.y; sacc.z += v.z; sacc.w += v.w;
        }
        float4 cv;
        cv.x = (sacc.x == 0.f) ? 1.f : 1.f / sacc.x;
        cv.y = (sacc.y == 0.f) ? 1.f : 1.f / sacc.y;
        cv.z = (sacc.z == 0.f) ? 1.f : 1.f / sacc.z;
        cv.w = (sacc.w == 0.f) ? 1.f : 1.f / sacc.w;
        *reinterpret_cast<float4*>(&lds[0][m0]) = cv;
    }
    __syncthreads();

    // phase 2: lane's 16 c values (4 tiles x 4 cols), masked to 0 beyond nc
    float cm[4][4];
#pragma unroll
    for (int t = 0; t < 4; ++t)
#pragma unroll
        for (int j = 0; j < 4; ++j) {
            const int m = t * 256 + lane * 4 + j;
            const float v = lds[0][m];
            cm[t][j] = (m < nc) ? v : 0.f;
        }
    __syncthreads();  // lds reused for the column-partial combine below

    // phase 3: rows — dot -> r_n, accumulate q*r_n into column accumulators
    float ca[4][4];
#pragma unroll
    for (int t = 0; t < 4; ++t)
#pragma unroll
        for (int j = 0; j < 4; ++j) ca[t][j] = 0.f;

    const int rbeg = p * RPC + wave * 16;
    const int rend = min(rbeg + 16, nr);
    const __half* qb = q + (size_t)b * N_ * M_;

    for (int n = rbeg; n < rend; ++n) {
        float f[4][4];
        float acc = 0.f;
#pragma unroll
        for (int t = 0; t < 4; ++t) {
            if (t * 256 < nc) {  // active tile (wave-uniform)
                const uint2 raw = *reinterpret_cast<const uint2*>(
                    qb + (size_t)n * M_ + t * 256 + lane * 4);
                dq4(raw, f[t]);
                acc = fmaf(f[t][0], cm[t][0], acc);
                acc = fmaf(f[t][1], cm[t][1], acc);
                acc = fmaf(f[t][2], cm[t][2], acc);
                acc = fmaf(f[t][3], cm[t][3], acc);
            }
        }
#pragma unroll
        for (int off = 1; off < 64; off <<= 1)
            acc += __shfl_xor(acc, off, 64);
        const float rn = 1.f / acc;  // acc > 0 always (q,c > 0 on valid cols)
#pragma unroll
        for (int t = 0; t < 4; ++t) {
            if (t * 256 < nc) {
                ca[t][0] = fmaf(f[t][0], rn, ca[t][0]);
                ca[t][1] = fmaf(f[t][1], rn, ca[t][1]);
                ca[t][2] = fmaf(f[t][2], rn, ca[t][2]);
                ca[t][3] = fmaf(f[t][3], rn, ca[t][3]);
            }
        }
    }

    // phase 4: combine 4 waves -> partial_out[b][p][:] (skipped tiles -> 0)
#pragma unroll
    for (int t = 0; t < 4; ++t) {
        const float4 v = {ca[t][0], ca[t][1], ca[t][2], ca[t][3]};
        *reinterpret_cast<float4*>(&lds[wave][t * 256 + lane * 4]) = v;
    }
    __syncthreads();
    const int m0 = threadIdx.x * 4;
    const float4 a0 = *reinterpret_cast<const float4*>(&lds[0][m0]);
    const float4 a1 = *reinterpret_cast<const float4*>(&lds[1][m0]);
    const float4 a2 = *reinterpret_cast<const float4*>(&lds[2][m0]);
    const float4 a3 = *reinterpret_cast<const float4*>(&lds[3][m0]);
    float4 o;
    o.x = a0.x + a1.x + a2.x + a3.x;
    o.y = a0.y + a1.y + a2.y + a3.y;
    o.z = a0.z + a1.z + a2.z + a3.z;
    o.w = a0.w + a1.w + a2.w + a3.w;
    *reinterpret_cast<float4*>(partial_out + ((size_t)b * PCHUNK + p) * M_ + m0) = o;
}

// ---------------------------------------------------------------------------
// Final: c8 = 1/reduce(partial_in); r9 = 1/(q c8); out = q*r9*c8 (float4
// stores). Skipped tiles / invalid rows -> zero stores without q reads.
// grid (PCHUNK, B), block 256 = 4 waves x 16 rows.
__global__ void final_pass_h(const __half* __restrict__ q,
                             const float* __restrict__ partial_in,
                             float* __restrict__ out,
                             const int* __restrict__ nrows,
                             const int* __restrict__ ncols) {
    __shared__ float ldsc[M_];
    const int b = blockIdx.y, p = blockIdx.x;
    const int nr = nrows[b], nc = ncols[b];
    const int lane = threadIdx.x & 63;

    {
        const int m0 = threadIdx.x * 4;
        const float* pp = partial_in + (size_t)b * PCHUNK * M_ + m0;
        float4 sacc = {0.f, 0.f, 0.f, 0.f};
#pragma unroll
        for (int i = 0; i < PCHUNK; ++i) {
            const float4 v = *reinterpret_cast<const float4*>(pp + (size_t)i * M_);
            sacc.x += v.x; sacc.y += v.y; sacc.z += v.z; sacc.w += v.w;
        }
        float4 cv;
        cv.x = (sacc.x == 0.f) ? 1.f : 1.f / sacc.x;
        cv.y = (sacc.y == 0.f) ? 1.f : 1.f / sacc.y;
        cv.z = (sacc.z == 0.f) ? 1.f : 1.f / sacc.z;
        cv.w = (sacc.w == 0.f) ? 1.f : 1.f / sacc.w;
        *reinterpret_cast<float4*>(&ldsc[m0]) = cv;
    }
    __syncthreads();

    float cm[4][4];
#pragma unroll
    for (int t = 0; t < 4; ++t)
#pragma unroll
        for (int j = 0; j < 4; ++j) {
            const int m = t * 256 + lane * 4 + j;
            const float v = ldsc[m];
            cm[t][j] = (m < nc) ? v : 0.f;
        }

    const int wave = threadIdx.x >> 6;
    const int rbeg = p * RPC + wave * 16;
    const __half* qb = q + (size_t)b * N_ * M_;
    float* ob = out + (size_t)b * N_ * M_;
    const float4 z = {0.f, 0.f, 0.f, 0.f};

    for (int n = rbeg; n < rbeg + 16; ++n) {
        if (n >= nr) {  // zero row (wave-uniform branch)
#pragma unroll
            for (int t = 0; t < 4; ++t)
                *reinterpret_cast<float4*>(ob + (size_t)n * M_ + t * 256 + lane * 4) = z;
            continue;
        }
        float f[4][4];
        float acc = 0.f;
#pragma unroll
        for (int t = 0; t < 4; ++t) {
            if (t * 256 < nc) {
                const uint2 raw = *reinterpret_cast<const uint2*>(
                    qb + (size_t)n * M_ + t * 256 + lane * 4);
                dq4(raw, f[t]);
                acc = fmaf(f[t][0], cm[t][0], acc);
                acc = fmaf(f[t][1], cm[t][1], acc);
                acc = fmaf(f[t][2], cm[t][2], acc);
                acc = fmaf(f[t][3], cm[t][3], acc);
            }
        }
#pragma unroll
        for (int off = 1; off < 64; off <<= 1)
            acc += __shfl_xor(acc, off, 64);
        const float rn = 1.f / acc;
#pragma unroll
        for (int t = 0; t < 4; ++t) {
            float4 o = z;
            if (t * 256 < nc) {  // inactive tile -> zeros (cm sliver handles rest)
                o.x = f[t][0] * rn * cm[t][0];
                o.y = f[t][1] * rn * cm[t][1];
                o.z = f[t][2] * rn * cm[t][2];
                o.w = f[t][3] * rn * cm[t][3];
            }
            *reinterpret_cast<float4*>(ob + (size_t)n * M_ + t * 256 + lane * 4) = o;
        }
    }
}

// ---------------------------------------------------------------------------
extern "C" void kernel_launch(void* const* d_in, const int* in_sizes, int n_in,
                              void* d_out, int out_size, void* d_ws, size_t ws_size,
                              hipStream_t stream) {
    const float* s = (const float*)d_in[0];
    const int* nrows = (const int*)d_in[1];
    const int* ncols = (const int*)d_in[2];
    float* out = (float*)d_out;

    const size_t qbytes = (size_t)B_ * N_ * M_ * sizeof(__half);  // 128 MiB
    __half* q = (__half*)d_ws;                                    // ws proven >= 136 MiB (R5-R10)
    float* pa = (float*)((char*)d_ws + qbytes);                   // 4 MiB
    float* pb = pa + (size_t)B_ * PCHUNK * M_;                    // 4 MiB

    const dim3 blk(256);
    const dim3 g_chunk(PCHUNK, B_);

    prep_pass<<<g_chunk, blk, 0, stream>>>(s, q, pa, nrows, ncols);
    fused_pass_h<<<g_chunk, blk, 0, stream>>>(q, pa, pb, nrows, ncols);  // c0 -> r1 -> p(c2)
    fused_pass_h<<<g_chunk, blk, 0, stream>>>(q, pb, pa, nrows, ncols);  // c2 -> r3 -> p(c4)
    fused_pass_h<<<g_chunk, blk, 0, stream>>>(q, pa, pb, nrows, ncols);  // c4 -> r5 -> p(c6)
    fused_pass_h<<<g_chunk, blk, 0, stream>>>(q, pb, pa, nrows, ncols);  // c6 -> r7 -> p(c8)
    final_pass_h<<<g_chunk, blk, 0, stream>>>(q, pa, out, nrows, ncols); // c8 -> r9 -> out
}

// Round 14
// 248.753 us; speedup vs baseline: 1.0793x; 1.0793x over previous
//
#include <hip/hip_runtime.h>
#include <hip/hip_fp16.h>

// Masked Sinkhorn via diagonal-scaling algebra on A = s+EPS:
//   c <- 1/(A^T r), r <- 1/(A c), out = A ∘ (r9 c8^T) on valid block.
// R14 = R7 bodies (best: 230us; 16B loads, full-width fp16 q, folded reduce)
// with ONE lever: PCHUNK 16 -> 32 (32 rows/block, 8 rows/wave, 2048 blocks)
// to lift occupancy from the measured 43-47% (R9/R10) toward 32 waves/CU.
// R13's tile-skipping REJECTED (268us: 8B loads cost more than skipped bytes).
// Partial ping-pong: pa in d_ws, pb in d_out head (d_out fully overwritten by
// final_pass afterwards, so it is legal scratch until then).

namespace {
constexpr int B_ = 64;
constexpr int N_ = 1024;
constexpr int M_ = 1024;
constexpr float EPS_ = 1e-4f;
constexpr int PCHUNK = 32;        // row chunks / blocks per batch (was 16)
constexpr int RPC = N_ / PCHUNK;  // 32 rows per block
constexpr int WROWS = RPC / 4;    // 8 rows per wave
}

typedef float f32x4_ __attribute__((ext_vector_type(4)));

__device__ __forceinline__ float4 nt_load4(const float* p) {
    f32x4_ v = __builtin_nontemporal_load(reinterpret_cast<const f32x4_*>(p));
    return float4{v.x, v.y, v.z, v.w};
}

// ---------------------------------------------------------------------------
// Prep: q = fp16(s+EPS) for valid rows (zeros for col-tiles beyond nc),
// plus iter-0 column-sum partials. grid (PCHUNK, B), block 256 = 4 waves x 8 rows.
__global__ void prep_pass(const float* __restrict__ s,
                          __half* __restrict__ q,
                          float* __restrict__ partial,
                          const int* __restrict__ nrows,
                          const int* __restrict__ ncols) {
    __shared__ float lds[4][M_];
    const int b = blockIdx.y, p = blockIdx.x;
    const int nr = nrows[b], nc = ncols[b];
    const int wave = threadIdx.x >> 6, lane = threadIdx.x & 63;

    float4 ca[4];
#pragma unroll
    for (int t = 0; t < 4; ++t) ca[t] = float4{0.f, 0.f, 0.f, 0.f};

    const int rbeg = p * RPC + wave * WROWS;
    const int rend = min(rbeg + WROWS, nr);
    const float* sb = s + (size_t)b * N_ * M_;
    __half* qb = q + (size_t)b * N_ * M_;

    for (int n = rbeg; n < rend; ++n) {
#pragma unroll
        for (int t = 0; t < 4; ++t) {
            const int m0 = t * 256 + lane * 4;
            float4 v = {0.f, 0.f, 0.f, 0.f};
            if (m0 < nc) {
                v = nt_load4(sb + (size_t)n * M_ + m0);
                v.x += EPS_; v.y += EPS_; v.z += EPS_; v.w += EPS_;
            }
            __half2 h01 = __floats2half2_rn(v.x, v.y);
            __half2 h23 = __floats2half2_rn(v.z, v.w);
            uint2 st;
            st.x = *reinterpret_cast<const unsigned*>(&h01);
            st.y = *reinterpret_cast<const unsigned*>(&h23);
            *reinterpret_cast<uint2*>(qb + (size_t)n * M_ + m0) = st;
            ca[t].x += v.x; ca[t].y += v.y; ca[t].z += v.z; ca[t].w += v.w;
        }
    }
#pragma unroll
    for (int t = 0; t < 4; ++t)
        *reinterpret_cast<float4*>(&lds[wave][t * 256 + lane * 4]) = ca[t];
    __syncthreads();
    const int m0 = threadIdx.x * 4;
    const float4 a0 = *reinterpret_cast<const float4*>(&lds[0][m0]);
    const float4 a1 = *reinterpret_cast<const float4*>(&lds[1][m0]);
    const float4 a2 = *reinterpret_cast<const float4*>(&lds[2][m0]);
    const float4 a3 = *reinterpret_cast<const float4*>(&lds[3][m0]);
    float4 o;
    o.x = a0.x + a1.x + a2.x + a3.x;
    o.y = a0.y + a1.y + a2.y + a3.y;
    o.z = a0.z + a1.z + a2.z + a3.z;
    o.w = a0.w + a1.w + a2.w + a3.w;
    *reinterpret_cast<float4*>(partial + ((size_t)b * PCHUNK + p) * M_ + m0) = o;
}

// ---------------------------------------------------------------------------
// Fused iteration pair: c = 1/reduce(partial_in) (folded, in LDS, identical
// order in every block -> bitwise-consistent); r = 1/(q c) per row; col
// partials of q^T r -> partial_out. Lane owns cols {t*512 + lane*8 .. +7}.
// grid (PCHUNK, B), block 256 = 4 waves x 8 rows.
__global__ void fused_pass_h(const __half* __restrict__ q,
                             const float* __restrict__ partial_in,
                             float* __restrict__ partial_out,
                             const int* __restrict__ nrows,
                             const int* __restrict__ ncols) {
    __shared__ float lds[4][M_];
    const int b = blockIdx.y, p = blockIdx.x;
    const int nr = nrows[b], nc = ncols[b];
    const int wave = threadIdx.x >> 6, lane = threadIdx.x & 63;

    // phase 1: c = 1/colsum into lds[0][.]
    {
        const int m0 = threadIdx.x * 4;
        const float* pp = partial_in + (size_t)b * PCHUNK * M_ + m0;
        float4 sacc = {0.f, 0.f, 0.f, 0.f};
#pragma unroll
        for (int i = 0; i < PCHUNK; ++i) {
            const float4 v = *reinterpret_cast<const float4*>(pp + (size_t)i * M_);
            sacc.x += v.x; sacc.y += v.y; sacc.z += v.z; sacc.w += v.w;
        }
        float4 cv;
        cv.x = (sacc.x == 0.f) ? 1.f : 1.f / sacc.x;
        cv.y = (sacc.y == 0.f) ? 1.f : 1.f / sacc.y;
        cv.z = (sacc.z == 0.f) ? 1.f : 1.f / sacc.z;
        cv.w = (sacc.w == 0.f) ? 1.f : 1.f / sacc.w;
        *reinterpret_cast<float4*>(&lds[0][m0]) = cv;
    }
    __syncthreads();

    // phase 2: lane's 16 c values, masked to 0 beyond nc
    float cm[16];
#pragma unroll
    for (int t = 0; t < 2; ++t)
#pragma unroll
        for (int j = 0; j < 8; ++j) {
            const int m = t * 512 + lane * 8 + j;
            const float v = lds[0][m];
            cm[t * 8 + j] = (m < nc) ? v : 0.f;
        }
    __syncthreads();  // lds reused for the column-partial combine below

    // phase 3: rows — dot -> r_n, accumulate q*r_n into column accumulators
    float ca[16];
#pragma unroll
    for (int k = 0; k < 16; ++k) ca[k] = 0.f;

    const int rbeg = p * RPC + wave * WROWS;
    const int rend = min(rbeg + WROWS, nr);
    const __half* qb = q + (size_t)b * N_ * M_;

    for (int n = rbeg; n < rend; ++n) {
        float f[16];
#pragma unroll
        for (int t = 0; t < 2; ++t) {
            const float4 raw = *reinterpret_cast<const float4*>(
                qb + (size_t)n * M_ + t * 512 + lane * 8);
            const __half2* hp = reinterpret_cast<const __half2*>(&raw);
#pragma unroll
            for (int k = 0; k < 4; ++k) {
                const float2 fr = __half22float2(hp[k]);
                f[t * 8 + 2 * k] = fr.x;
                f[t * 8 + 2 * k + 1] = fr.y;
            }
        }
        float acc = 0.f;
#pragma unroll
        for (int k = 0; k < 16; ++k) acc = fmaf(f[k], cm[k], acc);
#pragma unroll
        for (int off = 1; off < 64; off <<= 1)
            acc += __shfl_xor(acc, off, 64);
        const float rn = 1.f / acc;  // acc > 0 always (q,c > 0 on valid cols)
#pragma unroll
        for (int k = 0; k < 16; ++k) ca[k] = fmaf(f[k], rn, ca[k]);
    }

    // phase 4: combine 4 waves -> partial_out[b][p][:]
#pragma unroll
    for (int t = 0; t < 2; ++t) {
        float4 v0 = {ca[t * 8 + 0], ca[t * 8 + 1], ca[t * 8 + 2], ca[t * 8 + 3]};
        float4 v1 = {ca[t * 8 + 4], ca[t * 8 + 5], ca[t * 8 + 6], ca[t * 8 + 7]};
        *reinterpret_cast<float4*>(&lds[wave][t * 512 + lane * 8]) = v0;
        *reinterpret_cast<float4*>(&lds[wave][t * 512 + lane * 8 + 4]) = v1;
    }
    __syncthreads();
    const int m0 = threadIdx.x * 4;
    const float4 a0 = *reinterpret_cast<const float4*>(&lds[0][m0]);
    const float4 a1 = *reinterpret_cast<const float4*>(&lds[1][m0]);
    const float4 a2 = *reinterpret_cast<const float4*>(&lds[2][m0]);
    const float4 a3 = *reinterpret_cast<const float4*>(&lds[3][m0]);
    float4 o;
    o.x = a0.x + a1.x + a2.x + a3.x;
    o.y = a0.y + a1.y + a2.y + a3.y;
    o.z = a0.z + a1.z + a2.z + a3.z;
    o.w = a0.w + a1.w + a2.w + a3.w;
    *reinterpret_cast<float4*>(partial_out + ((size_t)b * PCHUNK + p) * M_ + m0) = o;
}

// ---------------------------------------------------------------------------
// Final: c8 = 1/reduce(partial_in); r9 = 1/(q c8); out = q*r9*c8 (regular
// float4 stores). Invalid rows/cols -> 0. grid (PCHUNK, B), 4 waves x 8 rows.
__global__ void final_pass_h(const __half* __restrict__ q,
                             const float* __restrict__ partial_in,
                             float* __restrict__ out,
                             const int* __restrict__ nrows,
                             const int* __restrict__ ncols) {
    __shared__ float ldsc[M_];
    const int b = blockIdx.y, p = blockIdx.x;
    const int nr = nrows[b], nc = ncols[b];
    const int wave = threadIdx.x >> 6, lane = threadIdx.x & 63;

    {
        const int m0 = threadIdx.x * 4;
        const float* pp = partial_in + (size_t)b * PCHUNK * M_ + m0;
        float4 sacc = {0.f, 0.f, 0.f, 0.f};
#pragma unroll
        for (int i = 0; i < PCHUNK; ++i) {
            const float4 v = *reinterpret_cast<const float4*>(pp + (size_t)i * M_);
            sacc.x += v.x; sacc.y += v.y; sacc.z += v.z; sacc.w += v.w;
        }
        float4 cv;
        cv.x = (sacc.x == 0.f) ? 1.f : 1.f / sacc.x;
        cv.y = (sacc.y == 0.f) ? 1.f : 1.f / sacc.y;
        cv.z = (sacc.z == 0.f) ? 1.f : 1.f / sacc.z;
        cv.w = (sacc.w == 0.f) ? 1.f : 1.f / sacc.w;
        *reinterpret_cast<float4*>(&ldsc[m0]) = cv;
    }
    __syncthreads();

    float cm[16];
#pragma unroll
    for (int t = 0; t < 2; ++t)
#pragma unroll
        for (int j = 0; j < 8; ++j) {
            const int m = t * 512 + lane * 8 + j;
            const float v = ldsc[m];
            cm[t * 8 + j] = (m < nc) ? v : 0.f;
        }

    const int rbeg = p * RPC + wave * WROWS;
    const __half* qb = q + (size_t)b * N_ * M_;
    float* ob = out + (size_t)b * N_ * M_;

    for (int n = rbeg; n < rbeg + WROWS; ++n) {
        if (n >= nr) {  // zero row (wave-uniform branch)
            const float4 z = {0.f, 0.f, 0.f, 0.f};
#pragma unroll
            for (int t = 0; t < 2; ++t) {
                *reinterpret_cast<float4*>(ob + (size_t)n * M_ + t * 512 + lane * 8) = z;
                *reinterpret_cast<float4*>(ob + (size_t)n * M_ + t * 512 + lane * 8 + 4) = z;
            }
            continue;
        }
        float f[16];
#pragma unroll
        for (int t = 0; t < 2; ++t) {
            const float4 raw = *reinterpret_cast<const float4*>(
                qb + (size_t)n * M_ + t * 512 + lane * 8);
            const __half2* hp = reinterpret_cast<const __half2*>(&raw);
#pragma unroll
            for (int k = 0; k < 4; ++k) {
                const float2 fr = __half22float2(hp[k]);
                f[t * 8 + 2 * k] = fr.x;
                f[t * 8 + 2 * k + 1] = fr.y;
            }
        }
        float acc = 0.f;
#pragma unroll
        for (int k = 0; k < 16; ++k) acc = fmaf(f[k], cm[k], acc);
#pragma unroll
        for (int off = 1; off < 64; off <<= 1)
            acc += __shfl_xor(acc, off, 64);
        const float rn = 1.f / acc;
#pragma unroll
        for (int t = 0; t < 2; ++t) {
            float4 o0, o1;
            o0.x = f[t * 8 + 0] * rn * cm[t * 8 + 0];
            o0.y = f[t * 8 + 1] * rn * cm[t * 8 + 1];
            o0.z = f[t * 8 + 2] * rn * cm[t * 8 + 2];
            o0.w = f[t * 8 + 3] * rn * cm[t * 8 + 3];
            o1.x = f[t * 8 + 4] * rn * cm[t * 8 + 4];
            o1.y = f[t * 8 + 5] * rn * cm[t * 8 + 5];
            o1.z = f[t * 8 + 6] * rn * cm[t * 8 + 6];
            o1.w = f[t * 8 + 7] * rn * cm[t * 8 + 7];
            *reinterpret_cast<float4*>(ob + (size_t)n * M_ + t * 512 + lane * 8) = o0;
            *reinterpret_cast<float4*>(ob + (size_t)n * M_ + t * 512 + lane * 8 + 4) = o1;
        }
    }
}

// ---------------------------------------------------------------------------
extern "C" void kernel_launch(void* const* d_in, const int* in_sizes, int n_in,
                              void* d_out, int out_size, void* d_ws, size_t ws_size,
                              hipStream_t stream) {
    const float* s = (const float*)d_in[0];
    const int* nrows = (const int*)d_in[1];
    const int* ncols = (const int*)d_in[2];
    float* out = (float*)d_out;

    const size_t qbytes = (size_t)B_ * N_ * M_ * sizeof(__half);  // 128 MiB
    __half* q = (__half*)d_ws;                                    // ws proven >= 136 MiB (R5-R10)
    float* pa = (float*)((char*)d_ws + qbytes);                   // 8 MiB (PCHUNK=32)
    // pb lives in the head of d_out: d_out is pure scratch until final_pass
    // overwrites every element. pb intermediates are consumed before that.
    float* pb = out;                                              // 8 MiB scratch

    const dim3 blk(256);
    const dim3 g_chunk(PCHUNK, B_);

    prep_pass<<<g_chunk, blk, 0, stream>>>(s, q, pa, nrows, ncols);
    fused_pass_h<<<g_chunk, blk, 0, stream>>>(q, pa, pb, nrows, ncols);  // c0 -> r1 -> p(c2)
    fused_pass_h<<<g_chunk, blk, 0, stream>>>(q, pb, pa, nrows, ncols);  // c2 -> r3 -> p(c4)
    fused_pass_h<<<g_chunk, blk, 0, stream>>>(q, pa, pb, nrows, ncols);  // c4 -> r5 -> p(c6)
    fused_pass_h<<<g_chunk, blk, 0, stream>>>(q, pb, pa, nrows, ncols);  // c6 -> r7 -> p(c8)
    final_pass_h<<<g_chunk, blk, 0, stream>>>(q, pa, out, nrows, ncols); // c8 -> r9 -> out
}

// Round 15
// 236.554 us; speedup vs baseline: 1.1350x; 1.0516x over previous
//
#include <hip/hip_runtime.h>
#include <hip/hip_fp16.h>

// Masked Sinkhorn via diagonal-scaling algebra on A = s+EPS:
//   c <- 1/(A^T r), r <- 1/(A c), out = A ∘ (r9 c8^T) on valid block.
// R15 = R7 (best: 230.5us) with ONE lever: 512-thread blocks (8 waves x 8
// rows) at the SAME grid (16,64) and identical per-pass traffic, to lift
// grid-limited occupancy 16 -> 32 waves/CU. __launch_bounds__(512,8) pins
// VGPR <= 64 (bodies measured exactly 64 in R10) for 8 waves/SIMD.
// R14's PCHUNK=32 REJECTED (249us: folded reduce traffic grew 64->256MB/pass).
// fp16 q (EPS baked in, zeros beyond nc); folded 16-slot c-reduce; regular
// float4 out stores (NT stores rejected in R6: 2.17x write amplification).

namespace {
constexpr int B_ = 64;
constexpr int N_ = 1024;
constexpr int M_ = 1024;
constexpr float EPS_ = 1e-4f;
constexpr int PCHUNK = 16;        // row chunks / blocks per batch
constexpr int RPC = N_ / PCHUNK;  // 64 rows per block
constexpr int NW = 8;             // waves per block
constexpr int WROWS = RPC / NW;   // 8 rows per wave
}

typedef float f32x4_ __attribute__((ext_vector_type(4)));

__device__ __forceinline__ float4 nt_load4(const float* p) {
    f32x4_ v = __builtin_nontemporal_load(reinterpret_cast<const f32x4_*>(p));
    return float4{v.x, v.y, v.z, v.w};
}

// ---------------------------------------------------------------------------
// Prep: q = fp16(s+EPS) for valid rows (zeros for col-tiles beyond nc),
// plus iter-0 column-sum partials. grid (PCHUNK, B), block 512 = 8 waves x 8 rows.
__global__ void __launch_bounds__(512, 8)
prep_pass(const float* __restrict__ s,
          __half* __restrict__ q,
          float* __restrict__ partial,
          const int* __restrict__ nrows,
          const int* __restrict__ ncols) {
    __shared__ float lds[NW][M_];
    const int b = blockIdx.y, p = blockIdx.x;
    const int nr = nrows[b], nc = ncols[b];
    const int wave = threadIdx.x >> 6, lane = threadIdx.x & 63;

    float4 ca[4];
#pragma unroll
    for (int t = 0; t < 4; ++t) ca[t] = float4{0.f, 0.f, 0.f, 0.f};

    const int rbeg = p * RPC + wave * WROWS;
    const int rend = min(rbeg + WROWS, nr);
    const float* sb = s + (size_t)b * N_ * M_;
    __half* qb = q + (size_t)b * N_ * M_;

    for (int n = rbeg; n < rend; ++n) {
#pragma unroll
        for (int t = 0; t < 4; ++t) {
            const int m0 = t * 256 + lane * 4;
            float4 v = {0.f, 0.f, 0.f, 0.f};
            if (m0 < nc) {
                v = nt_load4(sb + (size_t)n * M_ + m0);
                v.x += EPS_; v.y += EPS_; v.z += EPS_; v.w += EPS_;
            }
            __half2 h01 = __floats2half2_rn(v.x, v.y);
            __half2 h23 = __floats2half2_rn(v.z, v.w);
            uint2 st;
            st.x = *reinterpret_cast<const unsigned*>(&h01);
            st.y = *reinterpret_cast<const unsigned*>(&h23);
            *reinterpret_cast<uint2*>(qb + (size_t)n * M_ + m0) = st;
            ca[t].x += v.x; ca[t].y += v.y; ca[t].z += v.z; ca[t].w += v.w;
        }
    }
#pragma unroll
    for (int t = 0; t < 4; ++t)
        *reinterpret_cast<float4*>(&lds[wave][t * 256 + lane * 4]) = ca[t];
    __syncthreads();
    // combine 8 wave buffers; 512 threads x 2 cols
    const int m0 = threadIdx.x * 2;
    float2 acc = {0.f, 0.f};
#pragma unroll
    for (int w = 0; w < NW; ++w) {
        const float2 v = *reinterpret_cast<const float2*>(&lds[w][m0]);
        acc.x += v.x; acc.y += v.y;
    }
    *reinterpret_cast<float2*>(partial + ((size_t)b * PCHUNK + p) * M_ + m0) = acc;
}

// ---------------------------------------------------------------------------
// Fused iteration pair: c = 1/reduce(partial_in) (folded, in LDS, identical
// order in every block -> bitwise-consistent); r = 1/(q c) per row; col
// partials of q^T r -> partial_out. Lane owns cols {t*512 + lane*8 .. +7}.
// grid (PCHUNK, B), block 512 = 8 waves x 8 rows.
__global__ void __launch_bounds__(512, 8)
fused_pass_h(const __half* __restrict__ q,
             const float* __restrict__ partial_in,
             float* __restrict__ partial_out,
             const int* __restrict__ nrows,
             const int* __restrict__ ncols) {
    __shared__ float lds[NW][M_];
    const int b = blockIdx.y, p = blockIdx.x;
    const int nr = nrows[b], nc = ncols[b];
    const int wave = threadIdx.x >> 6, lane = threadIdx.x & 63;

    // phase 1: c = 1/colsum into lds[0][.]; 512 threads x 2 cols
    {
        const int m0 = threadIdx.x * 2;
        const float* pp = partial_in + (size_t)b * PCHUNK * M_ + m0;
        float2 sacc = {0.f, 0.f};
#pragma unroll
        for (int i = 0; i < PCHUNK; ++i) {
            const float2 v = *reinterpret_cast<const float2*>(pp + (size_t)i * M_);
            sacc.x += v.x; sacc.y += v.y;
        }
        float2 cv;
        cv.x = (sacc.x == 0.f) ? 1.f : 1.f / sacc.x;
        cv.y = (sacc.y == 0.f) ? 1.f : 1.f / sacc.y;
        *reinterpret_cast<float2*>(&lds[0][m0]) = cv;
    }
    __syncthreads();

    // phase 2: lane's 16 c values, masked to 0 beyond nc
    float cm[16];
#pragma unroll
    for (int t = 0; t < 2; ++t)
#pragma unroll
        for (int j = 0; j < 8; ++j) {
            const int m = t * 512 + lane * 8 + j;
            const float v = lds[0][m];
            cm[t * 8 + j] = (m < nc) ? v : 0.f;
        }
    __syncthreads();  // lds reused for the column-partial combine below

    // phase 3: rows — dot -> r_n, accumulate q*r_n into column accumulators
    float ca[16];
#pragma unroll
    for (int k = 0; k < 16; ++k) ca[k] = 0.f;

    const int rbeg = p * RPC + wave * WROWS;
    const int rend = min(rbeg + WROWS, nr);
    const __half* qb = q + (size_t)b * N_ * M_;

    for (int n = rbeg; n < rend; ++n) {
        float f[16];
#pragma unroll
        for (int t = 0; t < 2; ++t) {
            const float4 raw = *reinterpret_cast<const float4*>(
                qb + (size_t)n * M_ + t * 512 + lane * 8);
            const __half2* hp = reinterpret_cast<const __half2*>(&raw);
#pragma unroll
            for (int k = 0; k < 4; ++k) {
                const float2 fr = __half22float2(hp[k]);
                f[t * 8 + 2 * k] = fr.x;
                f[t * 8 + 2 * k + 1] = fr.y;
            }
        }
        float acc = 0.f;
#pragma unroll
        for (int k = 0; k < 16; ++k) acc = fmaf(f[k], cm[k], acc);
#pragma unroll
        for (int off = 1; off < 64; off <<= 1)
            acc += __shfl_xor(acc, off, 64);
        const float rn = 1.f / acc;  // acc > 0 always (q,c > 0 on valid cols)
#pragma unroll
        for (int k = 0; k < 16; ++k) ca[k] = fmaf(f[k], rn, ca[k]);
    }

    // phase 4: per-wave column partials -> LDS, combine 8 waves
#pragma unroll
    for (int t = 0; t < 2; ++t) {
        float4 v0 = {ca[t * 8 + 0], ca[t * 8 + 1], ca[t * 8 + 2], ca[t * 8 + 3]};
        float4 v1 = {ca[t * 8 + 4], ca[t * 8 + 5], ca[t * 8 + 6], ca[t * 8 + 7]};
        *reinterpret_cast<float4*>(&lds[wave][t * 512 + lane * 8]) = v0;
        *reinterpret_cast<float4*>(&lds[wave][t * 512 + lane * 8 + 4]) = v1;
    }
    __syncthreads();
    const int m0 = threadIdx.x * 2;
    float2 acc2 = {0.f, 0.f};
#pragma unroll
    for (int w = 0; w < NW; ++w) {
        const float2 v = *reinterpret_cast<const float2*>(&lds[w][m0]);
        acc2.x += v.x; acc2.y += v.y;
    }
    *reinterpret_cast<float2*>(partial_out + ((size_t)b * PCHUNK + p) * M_ + m0) = acc2;
}

// ---------------------------------------------------------------------------
// Final: c8 = 1/reduce(partial_in); r9 = 1/(q c8); out = q*r9*c8 (regular
// float4 stores). Invalid rows/cols -> 0. grid (PCHUNK, B), block 512.
__global__ void __launch_bounds__(512, 8)
final_pass_h(const __half* __restrict__ q,
             const float* __restrict__ partial_in,
             float* __restrict__ out,
             const int* __restrict__ nrows,
             const int* __restrict__ ncols) {
    __shared__ float ldsc[M_];
    const int b = blockIdx.y, p = blockIdx.x;
    const int nr = nrows[b], nc = ncols[b];
    const int wave = threadIdx.x >> 6, lane = threadIdx.x & 63;

    {
        const int m0 = threadIdx.x * 2;
        const float* pp = partial_in + (size_t)b * PCHUNK * M_ + m0;
        float2 sacc = {0.f, 0.f};
#pragma unroll
        for (int i = 0; i < PCHUNK; ++i) {
            const float2 v = *reinterpret_cast<const float2*>(pp + (size_t)i * M_);
            sacc.x += v.x; sacc.y += v.y;
        }
        float2 cv;
        cv.x = (sacc.x == 0.f) ? 1.f : 1.f / sacc.x;
        cv.y = (sacc.y == 0.f) ? 1.f : 1.f / sacc.y;
        *reinterpret_cast<float2*>(&ldsc[m0]) = cv;
    }
    __syncthreads();

    float cm[16];
#pragma unroll
    for (int t = 0; t < 2; ++t)
#pragma unroll
        for (int j = 0; j < 8; ++j) {
            const int m = t * 512 + lane * 8 + j;
            const float v = ldsc[m];
            cm[t * 8 + j] = (m < nc) ? v : 0.f;
        }

    const int rbeg = p * RPC + wave * WROWS;
    const __half* qb = q + (size_t)b * N_ * M_;
    float* ob = out + (size_t)b * N_ * M_;

    for (int n = rbeg; n < rbeg + WROWS; ++n) {
        if (n >= nr) {  // zero row (wave-uniform branch)
            const float4 z = {0.f, 0.f, 0.f, 0.f};
#pragma unroll
            for (int t = 0; t < 2; ++t) {
                *reinterpret_cast<float4*>(ob + (size_t)n * M_ + t * 512 + lane * 8) = z;
                *reinterpret_cast<float4*>(ob + (size_t)n * M_ + t * 512 + lane * 8 + 4) = z;
            }
            continue;
        }
        float f[16];
#pragma unroll
        for (int t = 0; t < 2; ++t) {
            const float4 raw = *reinterpret_cast<const float4*>(
                qb + (size_t)n * M_ + t * 512 + lane * 8);
            const __half2* hp = reinterpret_cast<const __half2*>(&raw);
#pragma unroll
            for (int k = 0; k < 4; ++k) {
                const float2 fr = __half22float2(hp[k]);
                f[t * 8 + 2 * k] = fr.x;
                f[t * 8 + 2 * k + 1] = fr.y;
            }
        }
        float acc = 0.f;
#pragma unroll
        for (int k = 0; k < 16; ++k) acc = fmaf(f[k], cm[k], acc);
#pragma unroll
        for (int off = 1; off < 64; off <<= 1)
            acc += __shfl_xor(acc, off, 64);
        const float rn = 1.f / acc;
#pragma unroll
        for (int t = 0; t < 2; ++t) {
            float4 o0, o1;
            o0.x = f[t * 8 + 0] * rn * cm[t * 8 + 0];
            o0.y = f[t * 8 + 1] * rn * cm[t * 8 + 1];
            o0.z = f[t * 8 + 2] * rn * cm[t * 8 + 2];
            o0.w = f[t * 8 + 3] * rn * cm[t * 8 + 3];
            o1.x = f[t * 8 + 4] * rn * cm[t * 8 + 4];
            o1.y = f[t * 8 + 5] * rn * cm[t * 8 + 5];
            o1.z = f[t * 8 + 6] * rn * cm[t * 8 + 6];
            o1.w = f[t * 8 + 7] * rn * cm[t * 8 + 7];
            *reinterpret_cast<float4*>(ob + (size_t)n * M_ + t * 512 + lane * 8) = o0;
            *reinterpret_cast<float4*>(ob + (size_t)n * M_ + t * 512 + lane * 8 + 4) = o1;
        }
    }
}

// ---------------------------------------------------------------------------
extern "C" void kernel_launch(void* const* d_in, const int* in_sizes, int n_in,
                              void* d_out, int out_size, void* d_ws, size_t ws_size,
                              hipStream_t stream) {
    const float* s = (const float*)d_in[0];
    const int* nrows = (const int*)d_in[1];
    const int* ncols = (const int*)d_in[2];
    float* out = (float*)d_out;

    const size_t qbytes = (size_t)B_ * N_ * M_ * sizeof(__half);  // 128 MiB
    __half* q = (__half*)d_ws;                                    // ws proven >= 136 MiB (R5-R10)
    float* pa = (float*)((char*)d_ws + qbytes);                   // 4 MiB
    float* pb = pa + (size_t)B_ * PCHUNK * M_;                    // 4 MiB

    const dim3 blk(512);
    const dim3 g_chunk(PCHUNK, B_);

    prep_pass<<<g_chunk, blk, 0, stream>>>(s, q, pa, nrows, ncols);
    fused_pass_h<<<g_chunk, blk, 0, stream>>>(q, pa, pb, nrows, ncols);  // c0 -> r1 -> p(c2)
    fused_pass_h<<<g_chunk, blk, 0, stream>>>(q, pb, pa, nrows, ncols);  // c2 -> r3 -> p(c4)
    fused_pass_h<<<g_chunk, blk, 0, stream>>>(q, pa, pb, nrows, ncols);  // c4 -> r5 -> p(c6)
    fused_pass_h<<<g_chunk, blk, 0, stream>>>(q, pb, pa, nrows, ncols);  // c6 -> r7 -> p(c8)
    final_pass_h<<<g_chunk, blk, 0, stream>>>(q, pa, out, nrows, ncols); // c8 -> r9 -> out
}

// Round 16
// 212.763 us; speedup vs baseline: 1.2619x; 1.1118x over previous
//
#include <hip/hip_runtime.h>
#include <hip/hip_fp16.h>

// Masked Sinkhorn via diagonal-scaling algebra on A = s+EPS:
//   c <- 1/(A^T r), r <- 1/(A c), out = A ∘ (r9 c8^T) on valid block.
// R16 = R7 (champion, 230.5us) + COMPACTED q ROW STRIDE W = roundup(nc,8):
// q shrinks 128 -> ~96MB avg (better L3 residency for the 5 re-reads) while
// keeping the exact 16B float4 load shape (R13's regression came from 8B
// loads, not the footprint idea). Lanes reading logical cols >= nc may pick
// up neighboring-row bytes: finite garbage, killed by the existing cm==0
// mask; dead ca columns are masked next pass; reads never leave the q slab.
// fp16 q (EPS baked in); folded c-reduce; regular float4 out stores.

namespace {
constexpr int B_ = 64;
constexpr int N_ = 1024;
constexpr int M_ = 1024;
constexpr float EPS_ = 1e-4f;
constexpr int PCHUNK = 16;        // row chunks / blocks per batch
constexpr int RPC = N_ / PCHUNK;  // 64 rows per chunk
}

typedef float f32x4_ __attribute__((ext_vector_type(4)));

__device__ __forceinline__ float4 nt_load4(const float* p) {
    f32x4_ v = __builtin_nontemporal_load(reinterpret_cast<const f32x4_*>(p));
    return float4{v.x, v.y, v.z, v.w};
}

// ---------------------------------------------------------------------------
// Prep: q[n*W + m] = fp16(s+EPS) for valid rows, m < W = roundup(nc,8)
// (zeros on the [nc,W) sliver), plus iter-0 column-sum partials.
// grid (PCHUNK, B), block 256 = 4 waves x 16 rows.
__global__ void prep_pass(const float* __restrict__ s,
                          __half* __restrict__ q,
                          float* __restrict__ partial,
                          const int* __restrict__ nrows,
                          const int* __restrict__ ncols) {
    __shared__ float lds[4][M_];
    const int b = blockIdx.y, p = blockIdx.x;
    const int nr = nrows[b], nc = ncols[b];
    const int W = (nc + 7) & ~7;  // compacted row stride (halves), 16B-aligned
    const int wave = threadIdx.x >> 6, lane = threadIdx.x & 63;

    float4 ca[4];
#pragma unroll
    for (int t = 0; t < 4; ++t) ca[t] = float4{0.f, 0.f, 0.f, 0.f};

    const int rbeg = p * RPC + wave * 16;
    const int rend = min(rbeg + 16, nr);
    const float* sb = s + (size_t)b * N_ * M_;
    __half* qb = q + (size_t)b * N_ * M_;

    for (int n = rbeg; n < rend; ++n) {
#pragma unroll
        for (int t = 0; t < 4; ++t) {
            const int m0 = t * 256 + lane * 4;
            float4 v = {0.f, 0.f, 0.f, 0.f};
            if (m0 < nc) {
                v = nt_load4(sb + (size_t)n * M_ + m0);
                v.x += EPS_; v.y += EPS_; v.z += EPS_; v.w += EPS_;
            }
            if (m0 < W) {  // compact write (zeros on the [nc,W) sliver)
                __half2 h01 = __floats2half2_rn(v.x, v.y);
                __half2 h23 = __floats2half2_rn(v.z, v.w);
                uint2 st;
                st.x = *reinterpret_cast<const unsigned*>(&h01);
                st.y = *reinterpret_cast<const unsigned*>(&h23);
                *reinterpret_cast<uint2*>(qb + (size_t)n * W + m0) = st;
            }
            ca[t].x += v.x; ca[t].y += v.y; ca[t].z += v.z; ca[t].w += v.w;
        }
    }
#pragma unroll
    for (int t = 0; t < 4; ++t)
        *reinterpret_cast<float4*>(&lds[wave][t * 256 + lane * 4]) = ca[t];
    __syncthreads();
    const int m0 = threadIdx.x * 4;
    const float4 a0 = *reinterpret_cast<const float4*>(&lds[0][m0]);
    const float4 a1 = *reinterpret_cast<const float4*>(&lds[1][m0]);
    const float4 a2 = *reinterpret_cast<const float4*>(&lds[2][m0]);
    const float4 a3 = *reinterpret_cast<const float4*>(&lds[3][m0]);
    float4 o;
    o.x = a0.x + a1.x + a2.x + a3.x;
    o.y = a0.y + a1.y + a2.y + a3.y;
    o.z = a0.z + a1.z + a2.z + a3.z;
    o.w = a0.w + a1.w + a2.w + a3.w;
    *reinterpret_cast<float4*>(partial + ((size_t)b * PCHUNK + p) * M_ + m0) = o;
}

// ---------------------------------------------------------------------------
// Fused iteration pair: c = 1/reduce(partial_in) (folded, identical order in
// every block); r = 1/(q c) per row; col partials of q^T r -> partial_out.
// q read at compact stride W; cm==0 kills cols >= nc (incl. cross-row reads).
// grid (PCHUNK, B), block 256 = 4 waves x 16 rows.
__global__ void fused_pass_h(const __half* __restrict__ q,
                             const float* __restrict__ partial_in,
                             float* __restrict__ partial_out,
                             const int* __restrict__ nrows,
                             const int* __restrict__ ncols) {
    __shared__ float lds[4][M_];
    const int b = blockIdx.y, p = blockIdx.x;
    const int nr = nrows[b], nc = ncols[b];
    const int W = (nc + 7) & ~7;
    const int wave = threadIdx.x >> 6, lane = threadIdx.x & 63;

    // phase 1: c = 1/colsum into lds[0][.]
    {
        const int m0 = threadIdx.x * 4;
        const float* pp = partial_in + (size_t)b * PCHUNK * M_ + m0;
        float4 sacc = {0.f, 0.f, 0.f, 0.f};
#pragma unroll
        for (int i = 0; i < PCHUNK; ++i) {
            const float4 v = *reinterpret_cast<const float4*>(pp + (size_t)i * M_);
            sacc.x += v.x; sacc.y += v.y; sacc.z += v.z; sacc.w += v.w;
        }
        float4 cv;
        cv.x = (sacc.x == 0.f) ? 1.f : 1.f / sacc.x;
        cv.y = (sacc.y == 0.f) ? 1.f : 1.f / sacc.y;
        cv.z = (sacc.z == 0.f) ? 1.f : 1.f / sacc.z;
        cv.w = (sacc.w == 0.f) ? 1.f : 1.f / sacc.w;
        *reinterpret_cast<float4*>(&lds[0][m0]) = cv;
    }
    __syncthreads();

    // phase 2: lane's 16 c values, masked to 0 beyond nc
    float cm[16];
#pragma unroll
    for (int t = 0; t < 2; ++t)
#pragma unroll
        for (int j = 0; j < 8; ++j) {
            const int m = t * 512 + lane * 8 + j;
            const float v = lds[0][m];
            cm[t * 8 + j] = (m < nc) ? v : 0.f;
        }
    __syncthreads();  // lds reused for the column-partial combine below

    // phase 3: rows — dot -> r_n, accumulate q*r_n into column accumulators
    float ca[16];
#pragma unroll
    for (int k = 0; k < 16; ++k) ca[k] = 0.f;

    const int rbeg = p * RPC + wave * 16;
    const int rend = min(rbeg + 16, nr);
    const __half* qb = q + (size_t)b * N_ * M_;

    for (int n = rbeg; n < rend; ++n) {
        float f[16];
#pragma unroll
        for (int t = 0; t < 2; ++t) {
            const float4 raw = *reinterpret_cast<const float4*>(
                qb + (size_t)n * W + t * 512 + lane * 8);
            const __half2* hp = reinterpret_cast<const __half2*>(&raw);
#pragma unroll
            for (int k = 0; k < 4; ++k) {
                const float2 fr = __half22float2(hp[k]);
                f[t * 8 + 2 * k] = fr.x;
                f[t * 8 + 2 * k + 1] = fr.y;
            }
        }
        float acc = 0.f;
#pragma unroll
        for (int k = 0; k < 16; ++k) acc = fmaf(f[k], cm[k], acc);
#pragma unroll
        for (int off = 1; off < 64; off <<= 1)
            acc += __shfl_xor(acc, off, 64);
        const float rn = 1.f / acc;  // acc > 0 always (q,c > 0 on valid cols)
#pragma unroll
        for (int k = 0; k < 16; ++k) ca[k] = fmaf(f[k], rn, ca[k]);
    }

    // phase 4: combine 4 waves -> partial_out[b][p][:]
    // (cols >= nc carry garbage; they are masked by cm on the next pass)
#pragma unroll
    for (int t = 0; t < 2; ++t) {
        float4 v0 = {ca[t * 8 + 0], ca[t * 8 + 1], ca[t * 8 + 2], ca[t * 8 + 3]};
        float4 v1 = {ca[t * 8 + 4], ca[t * 8 + 5], ca[t * 8 + 6], ca[t * 8 + 7]};
        *reinterpret_cast<float4*>(&lds[wave][t * 512 + lane * 8]) = v0;
        *reinterpret_cast<float4*>(&lds[wave][t * 512 + lane * 8 + 4]) = v1;
    }
    __syncthreads();
    const int m0 = threadIdx.x * 4;
    const float4 a0 = *reinterpret_cast<const float4*>(&lds[0][m0]);
    const float4 a1 = *reinterpret_cast<const float4*>(&lds[1][m0]);
    const float4 a2 = *reinterpret_cast<const float4*>(&lds[2][m0]);
    const float4 a3 = *reinterpret_cast<const float4*>(&lds[3][m0]);
    float4 o;
    o.x = a0.x + a1.x + a2.x + a3.x;
    o.y = a0.y + a1.y + a2.y + a3.y;
    o.z = a0.z + a1.z + a2.z + a3.z;
    o.w = a0.w + a1.w + a2.w + a3.w;
    *reinterpret_cast<float4*>(partial_out + ((size_t)b * PCHUNK + p) * M_ + m0) = o;
}

// ---------------------------------------------------------------------------
// Final: c8 = 1/reduce(partial_in); r9 = 1/(q c8); out = q*r9*c8 (regular
// float4 stores at full 1024 stride). cm==0 zeroes cols >= nc.
// grid (PCHUNK, B), block 256 = 4 waves x 16 rows.
__global__ void final_pass_h(const __half* __restrict__ q,
                             const float* __restrict__ partial_in,
                             float* __restrict__ out,
                             const int* __restrict__ nrows,
                             const int* __restrict__ ncols) {
    __shared__ float ldsc[M_];
    const int b = blockIdx.y, p = blockIdx.x;
    const int nr = nrows[b], nc = ncols[b];
    const int W = (nc + 7) & ~7;
    const int wave = threadIdx.x >> 6, lane = threadIdx.x & 63;

    {
        const int m0 = threadIdx.x * 4;
        const float* pp = partial_in + (size_t)b * PCHUNK * M_ + m0;
        float4 sacc = {0.f, 0.f, 0.f, 0.f};
#pragma unroll
        for (int i = 0; i < PCHUNK; ++i) {
            const float4 v = *reinterpret_cast<const float4*>(pp + (size_t)i * M_);
            sacc.x += v.x; sacc.y += v.y; sacc.z += v.z; sacc.w += v.w;
        }
        float4 cv;
        cv.x = (sacc.x == 0.f) ? 1.f : 1.f / sacc.x;
        cv.y = (sacc.y == 0.f) ? 1.f : 1.f / sacc.y;
        cv.z = (sacc.z == 0.f) ? 1.f : 1.f / sacc.z;
        cv.w = (sacc.w == 0.f) ? 1.f : 1.f / sacc.w;
        *reinterpret_cast<float4*>(&ldsc[m0]) = cv;
    }
    __syncthreads();

    float cm[16];
#pragma unroll
    for (int t = 0; t < 2; ++t)
#pragma unroll
        for (int j = 0; j < 8; ++j) {
            const int m = t * 512 + lane * 8 + j;
            const float v = ldsc[m];
            cm[t * 8 + j] = (m < nc) ? v : 0.f;
        }

    const int rbeg = p * RPC + wave * 16;
    const __half* qb = q + (size_t)b * N_ * M_;
    float* ob = out + (size_t)b * N_ * M_;

    for (int n = rbeg; n < rbeg + 16; ++n) {
        if (n >= nr) {  // zero row (wave-uniform branch)
            const float4 z = {0.f, 0.f, 0.f, 0.f};
#pragma unroll
            for (int t = 0; t < 2; ++t) {
                *reinterpret_cast<float4*>(ob + (size_t)n * M_ + t * 512 + lane * 8) = z;
                *reinterpret_cast<float4*>(ob + (size_t)n * M_ + t * 512 + lane * 8 + 4) = z;
            }
            continue;
        }
        float f[16];
#pragma unroll
        for (int t = 0; t < 2; ++t) {
            const float4 raw = *reinterpret_cast<const float4*>(
                qb + (size_t)n * W + t * 512 + lane * 8);
            const __half2* hp = reinterpret_cast<const __half2*>(&raw);
#pragma unroll
            for (int k = 0; k < 4; ++k) {
                const float2 fr = __half22float2(hp[k]);
                f[t * 8 + 2 * k] = fr.x;
                f[t * 8 + 2 * k + 1] = fr.y;
            }
        }
        float acc = 0.f;
#pragma unroll
        for (int k = 0; k < 16; ++k) acc = fmaf(f[k], cm[k], acc);
#pragma unroll
        for (int off = 1; off < 64; off <<= 1)
            acc += __shfl_xor(acc, off, 64);
        const float rn = 1.f / acc;
#pragma unroll
        for (int t = 0; t < 2; ++t) {
            float4 o0, o1;
            o0.x = f[t * 8 + 0] * rn * cm[t * 8 + 0];  // cm=0 beyond nc -> 0
            o0.y = f[t * 8 + 1] * rn * cm[t * 8 + 1];
            o0.z = f[t * 8 + 2] * rn * cm[t * 8 + 2];
            o0.w = f[t * 8 + 3] * rn * cm[t * 8 + 3];
            o1.x = f[t * 8 + 4] * rn * cm[t * 8 + 4];
            o1.y = f[t * 8 + 5] * rn * cm[t * 8 + 5];
            o1.z = f[t * 8 + 6] * rn * cm[t * 8 + 6];
            o1.w = f[t * 8 + 7] * rn * cm[t * 8 + 7];
            *reinterpret_cast<float4*>(ob + (size_t)n * M_ + t * 512 + lane * 8) = o0;
            *reinterpret_cast<float4*>(ob + (size_t)n * M_ + t * 512 + lane * 8 + 4) = o1;
        }
    }
}

// ---------------------------------------------------------------------------
extern "C" void kernel_launch(void* const* d_in, const int* in_sizes, int n_in,
                              void* d_out, int out_size, void* d_ws, size_t ws_size,
                              hipStream_t stream) {
    const float* s = (const float*)d_in[0];
    const int* nrows = (const int*)d_in[1];
    const int* ncols = (const int*)d_in[2];
    float* out = (float*)d_out;

    const size_t qbytes = (size_t)B_ * N_ * M_ * sizeof(__half);  // 128 MiB slab (W<=1024 per row)
    __half* q = (__half*)d_ws;                                    // ws proven >= 136 MiB (R5-R10)
    float* pa = (float*)((char*)d_ws + qbytes);                   // 4 MiB
    float* pb = pa + (size_t)B_ * PCHUNK * M_;                    // 4 MiB

    const dim3 blk(256);
    const dim3 g_chunk(PCHUNK, B_);

    prep_pass<<<g_chunk, blk, 0, stream>>>(s, q, pa, nrows, ncols);
    fused_pass_h<<<g_chunk, blk, 0, stream>>>(q, pa, pb, nrows, ncols);  // c0 -> r1 -> p(c2)
    fused_pass_h<<<g_chunk, blk, 0, stream>>>(q, pb, pa, nrows, ncols);  // c2 -> r3 -> p(c4)
    fused_pass_h<<<g_chunk, blk, 0, stream>>>(q, pa, pb, nrows, ncols);  // c4 -> r5 -> p(c6)
    fused_pass_h<<<g_chunk, blk, 0, stream>>>(q, pb, pa, nrows, ncols);  // c6 -> r7 -> p(c8)
    final_pass_h<<<g_chunk, blk, 0, stream>>>(q, pa, out, nrows, ncols); // c8 -> r9 -> out
}

// Round 17
// 210.947 us; speedup vs baseline: 1.2727x; 1.0086x over previous
//
#include <hip/hip_runtime.h>
#include <hip/hip_fp16.h>

// Masked Sinkhorn via diagonal-scaling algebra on A = s+EPS:
//   c <- 1/(A^T r), r <- 1/(A c), out = A ∘ (r9 c8^T) on valid block.
// R17 = R16 (champion, 212.8us: compacted q stride W=roundup(nc,8)) + mild
// ILP in the latency-bound inner loops: 4-way split dot chains and 2-row
// pairing (two independent shfl butterflies in flight). ca-update order kept
// (n then n+1) -> only intra-row dot summation order changes (rounding).
// R6-style 8-row batching REJECTED earlier (register pressure); pairs are
// cheap (+~16 VGPR, still <=128 -> no occupancy loss at 16 waves/CU).

namespace {
constexpr int B_ = 64;
constexpr int N_ = 1024;
constexpr int M_ = 1024;
constexpr float EPS_ = 1e-4f;
constexpr int PCHUNK = 16;        // row chunks / blocks per batch
constexpr int RPC = N_ / PCHUNK;  // 64 rows per chunk
}

typedef float f32x4_ __attribute__((ext_vector_type(4)));

__device__ __forceinline__ float4 nt_load4(const float* p) {
    f32x4_ v = __builtin_nontemporal_load(reinterpret_cast<const f32x4_*>(p));
    return float4{v.x, v.y, v.z, v.w};
}

// Load one compacted q row segment (16 fp16) and dequant to f[16].
__device__ __forceinline__ void load_row16(const __half* qb, size_t base,
                                           int lane, float* f) {
#pragma unroll
    for (int t = 0; t < 2; ++t) {
        const float4 raw = *reinterpret_cast<const float4*>(
            qb + base + t * 512 + lane * 8);
        const __half2* hp = reinterpret_cast<const __half2*>(&raw);
#pragma unroll
        for (int k = 0; k < 4; ++k) {
            const float2 fr = __half22float2(hp[k]);
            f[t * 8 + 2 * k] = fr.x;
            f[t * 8 + 2 * k + 1] = fr.y;
        }
    }
}

// 4-way split dot: f[16] . cm[16]
__device__ __forceinline__ float dot16(const float* f, const float* cm) {
    float a0 = 0.f, a1 = 0.f, a2 = 0.f, a3 = 0.f;
#pragma unroll
    for (int k = 0; k < 4; ++k) {
        a0 = fmaf(f[k], cm[k], a0);
        a1 = fmaf(f[4 + k], cm[4 + k], a1);
        a2 = fmaf(f[8 + k], cm[8 + k], a2);
        a3 = fmaf(f[12 + k], cm[12 + k], a3);
    }
    return (a0 + a1) + (a2 + a3);
}

// ---------------------------------------------------------------------------
// Prep: q[n*W + m] = fp16(s+EPS) for valid rows, m < W = roundup(nc,8)
// (zeros on the [nc,W) sliver), plus iter-0 column-sum partials.
// grid (PCHUNK, B), block 256 = 4 waves x 16 rows.
__global__ void prep_pass(const float* __restrict__ s,
                          __half* __restrict__ q,
                          float* __restrict__ partial,
                          const int* __restrict__ nrows,
                          const int* __restrict__ ncols) {
    __shared__ float lds[4][M_];
    const int b = blockIdx.y, p = blockIdx.x;
    const int nr = nrows[b], nc = ncols[b];
    const int W = (nc + 7) & ~7;  // compacted row stride (halves), 16B-aligned
    const int wave = threadIdx.x >> 6, lane = threadIdx.x & 63;

    float4 ca[4];
#pragma unroll
    for (int t = 0; t < 4; ++t) ca[t] = float4{0.f, 0.f, 0.f, 0.f};

    const int rbeg = p * RPC + wave * 16;
    const int rend = min(rbeg + 16, nr);
    const float* sb = s + (size_t)b * N_ * M_;
    __half* qb = q + (size_t)b * N_ * M_;

    for (int n = rbeg; n < rend; ++n) {
#pragma unroll
        for (int t = 0; t < 4; ++t) {
            const int m0 = t * 256 + lane * 4;
            float4 v = {0.f, 0.f, 0.f, 0.f};
            if (m0 < nc) {
                v = nt_load4(sb + (size_t)n * M_ + m0);
                v.x += EPS_; v.y += EPS_; v.z += EPS_; v.w += EPS_;
            }
            if (m0 < W) {  // compact write (zeros on the [nc,W) sliver)
                __half2 h01 = __floats2half2_rn(v.x, v.y);
                __half2 h23 = __floats2half2_rn(v.z, v.w);
                uint2 st;
                st.x = *reinterpret_cast<const unsigned*>(&h01);
                st.y = *reinterpret_cast<const unsigned*>(&h23);
                *reinterpret_cast<uint2*>(qb + (size_t)n * W + m0) = st;
            }
            ca[t].x += v.x; ca[t].y += v.y; ca[t].z += v.z; ca[t].w += v.w;
        }
    }
#pragma unroll
    for (int t = 0; t < 4; ++t)
        *reinterpret_cast<float4*>(&lds[wave][t * 256 + lane * 4]) = ca[t];
    __syncthreads();
    const int m0 = threadIdx.x * 4;
    const float4 a0 = *reinterpret_cast<const float4*>(&lds[0][m0]);
    const float4 a1 = *reinterpret_cast<const float4*>(&lds[1][m0]);
    const float4 a2 = *reinterpret_cast<const float4*>(&lds[2][m0]);
    const float4 a3 = *reinterpret_cast<const float4*>(&lds[3][m0]);
    float4 o;
    o.x = a0.x + a1.x + a2.x + a3.x;
    o.y = a0.y + a1.y + a2.y + a3.y;
    o.z = a0.z + a1.z + a2.z + a3.z;
    o.w = a0.w + a1.w + a2.w + a3.w;
    *reinterpret_cast<float4*>(partial + ((size_t)b * PCHUNK + p) * M_ + m0) = o;
}

// ---------------------------------------------------------------------------
// Fused iteration pair: c = 1/reduce(partial_in) (folded, identical order in
// every block); r = 1/(q c) per row; col partials of q^T r -> partial_out.
// 2-row pairing + split dot chains. grid (PCHUNK, B), block 256 = 4w x 16r.
__global__ void fused_pass_h(const __half* __restrict__ q,
                             const float* __restrict__ partial_in,
                             float* __restrict__ partial_out,
                             const int* __restrict__ nrows,
                             const int* __restrict__ ncols) {
    __shared__ float lds[4][M_];
    const int b = blockIdx.y, p = blockIdx.x;
    const int nr = nrows[b], nc = ncols[b];
    const int W = (nc + 7) & ~7;
    const int wave = threadIdx.x >> 6, lane = threadIdx.x & 63;

    // phase 1: c = 1/colsum into lds[0][.]
    {
        const int m0 = threadIdx.x * 4;
        const float* pp = partial_in + (size_t)b * PCHUNK * M_ + m0;
        float4 sacc = {0.f, 0.f, 0.f, 0.f};
#pragma unroll
        for (int i = 0; i < PCHUNK; ++i) {
            const float4 v = *reinterpret_cast<const float4*>(pp + (size_t)i * M_);
            sacc.x += v.x; sacc.y += v.y; sacc.z += v.z; sacc.w += v.w;
        }
        float4 cv;
        cv.x = (sacc.x == 0.f) ? 1.f : 1.f / sacc.x;
        cv.y = (sacc.y == 0.f) ? 1.f : 1.f / sacc.y;
        cv.z = (sacc.z == 0.f) ? 1.f : 1.f / sacc.z;
        cv.w = (sacc.w == 0.f) ? 1.f : 1.f / sacc.w;
        *reinterpret_cast<float4*>(&lds[0][m0]) = cv;
    }
    __syncthreads();

    // phase 2: lane's 16 c values, masked to 0 beyond nc
    float cm[16];
#pragma unroll
    for (int t = 0; t < 2; ++t)
#pragma unroll
        for (int j = 0; j < 8; ++j) {
            const int m = t * 512 + lane * 8 + j;
            const float v = lds[0][m];
            cm[t * 8 + j] = (m < nc) ? v : 0.f;
        }
    __syncthreads();  // lds reused for the column-partial combine below

    // phase 3: rows in PAIRS — two dots, two interleaved butterflies,
    // ca updates in original (n, n+1) order.
    float ca[16];
#pragma unroll
    for (int k = 0; k < 16; ++k) ca[k] = 0.f;

    const int rbeg = p * RPC + wave * 16;
    const int rend = min(rbeg + 16, nr);
    const __half* qb = q + (size_t)b * N_ * M_;

    int n = rbeg;
    for (; n + 1 < rend; n += 2) {
        float f0[16], f1[16];
        load_row16(qb, (size_t)n * W, lane, f0);
        load_row16(qb, (size_t)(n + 1) * W, lane, f1);
        float acc0 = dot16(f0, cm);
        float acc1 = dot16(f1, cm);
#pragma unroll
        for (int off = 1; off < 64; off <<= 1) {
            acc0 += __shfl_xor(acc0, off, 64);
            acc1 += __shfl_xor(acc1, off, 64);
        }
        const float rn0 = 1.f / acc0;
        const float rn1 = 1.f / acc1;
#pragma unroll
        for (int k = 0; k < 16; ++k) ca[k] = fmaf(f0[k], rn0, ca[k]);
#pragma unroll
        for (int k = 0; k < 16; ++k) ca[k] = fmaf(f1[k], rn1, ca[k]);
    }
    if (n < rend) {  // odd tail row
        float f0[16];
        load_row16(qb, (size_t)n * W, lane, f0);
        float acc0 = dot16(f0, cm);
#pragma unroll
        for (int off = 1; off < 64; off <<= 1)
            acc0 += __shfl_xor(acc0, off, 64);
        const float rn0 = 1.f / acc0;
#pragma unroll
        for (int k = 0; k < 16; ++k) ca[k] = fmaf(f0[k], rn0, ca[k]);
    }

    // phase 4: combine 4 waves -> partial_out[b][p][:]
    // (cols >= nc carry garbage; they are masked by cm on the next pass)
#pragma unroll
    for (int t = 0; t < 2; ++t) {
        float4 v0 = {ca[t * 8 + 0], ca[t * 8 + 1], ca[t * 8 + 2], ca[t * 8 + 3]};
        float4 v1 = {ca[t * 8 + 4], ca[t * 8 + 5], ca[t * 8 + 6], ca[t * 8 + 7]};
        *reinterpret_cast<float4*>(&lds[wave][t * 512 + lane * 8]) = v0;
        *reinterpret_cast<float4*>(&lds[wave][t * 512 + lane * 8 + 4]) = v1;
    }
    __syncthreads();
    const int m0 = threadIdx.x * 4;
    const float4 a0 = *reinterpret_cast<const float4*>(&lds[0][m0]);
    const float4 a1 = *reinterpret_cast<const float4*>(&lds[1][m0]);
    const float4 a2 = *reinterpret_cast<const float4*>(&lds[2][m0]);
    const float4 a3 = *reinterpret_cast<const float4*>(&lds[3][m0]);
    float4 o;
    o.x = a0.x + a1.x + a2.x + a3.x;
    o.y = a0.y + a1.y + a2.y + a3.y;
    o.z = a0.z + a1.z + a2.z + a3.z;
    o.w = a0.w + a1.w + a2.w + a3.w;
    *reinterpret_cast<float4*>(partial_out + ((size_t)b * PCHUNK + p) * M_ + m0) = o;
}

// ---------------------------------------------------------------------------
// Final: c8 = 1/reduce(partial_in); r9 = 1/(q c8); out = q*r9*c8 (regular
// float4 stores at full 1024 stride). cm==0 zeroes cols >= nc.
// grid (PCHUNK, B), block 256 = 4 waves x 16 rows.
__global__ void final_pass_h(const __half* __restrict__ q,
                             const float* __restrict__ partial_in,
                             float* __restrict__ out,
                             const int* __restrict__ nrows,
                             const int* __restrict__ ncols) {
    __shared__ float ldsc[M_];
    const int b = blockIdx.y, p = blockIdx.x;
    const int nr = nrows[b], nc = ncols[b];
    const int W = (nc + 7) & ~7;
    const int wave = threadIdx.x >> 6, lane = threadIdx.x & 63;

    {
        const int m0 = threadIdx.x * 4;
        const float* pp = partial_in + (size_t)b * PCHUNK * M_ + m0;
        float4 sacc = {0.f, 0.f, 0.f, 0.f};
#pragma unroll
        for (int i = 0; i < PCHUNK; ++i) {
            const float4 v = *reinterpret_cast<const float4*>(pp + (size_t)i * M_);
            sacc.x += v.x; sacc.y += v.y; sacc.z += v.z; sacc.w += v.w;
        }
        float4 cv;
        cv.x = (sacc.x == 0.f) ? 1.f : 1.f / sacc.x;
        cv.y = (sacc.y == 0.f) ? 1.f : 1.f / sacc.y;
        cv.z = (sacc.z == 0.f) ? 1.f : 1.f / sacc.z;
        cv.w = (sacc.w == 0.f) ? 1.f : 1.f / sacc.w;
        *reinterpret_cast<float4*>(&ldsc[m0]) = cv;
    }
    __syncthreads();

    float cm[16];
#pragma unroll
    for (int t = 0; t < 2; ++t)
#pragma unroll
        for (int j = 0; j < 8; ++j) {
            const int m = t * 512 + lane * 8 + j;
            const float v = ldsc[m];
            cm[t * 8 + j] = (m < nc) ? v : 0.f;
        }

    const int rbeg = p * RPC + wave * 16;
    const __half* qb = q + (size_t)b * N_ * M_;
    float* ob = out + (size_t)b * N_ * M_;

    for (int n = rbeg; n < rbeg + 16; ++n) {
        if (n >= nr) {  // zero row (wave-uniform branch)
            const float4 z = {0.f, 0.f, 0.f, 0.f};
#pragma unroll
            for (int t = 0; t < 2; ++t) {
                *reinterpret_cast<float4*>(ob + (size_t)n * M_ + t * 512 + lane * 8) = z;
                *reinterpret_cast<float4*>(ob + (size_t)n * M_ + t * 512 + lane * 8 + 4) = z;
            }
            continue;
        }
        float f[16];
        load_row16(qb, (size_t)n * W, lane, f);
        float acc = dot16(f, cm);
#pragma unroll
        for (int off = 1; off < 64; off <<= 1)
            acc += __shfl_xor(acc, off, 64);
        const float rn = 1.f / acc;
#pragma unroll
        for (int t = 0; t < 2; ++t) {
            float4 o0, o1;
            o0.x = f[t * 8 + 0] * rn * cm[t * 8 + 0];  // cm=0 beyond nc -> 0
            o0.y = f[t * 8 + 1] * rn * cm[t * 8 + 1];
            o0.z = f[t * 8 + 2] * rn * cm[t * 8 + 2];
            o0.w = f[t * 8 + 3] * rn * cm[t * 8 + 3];
            o1.x = f[t * 8 + 4] * rn * cm[t * 8 + 4];
            o1.y = f[t * 8 + 5] * rn * cm[t * 8 + 5];
            o1.z = f[t * 8 + 6] * rn * cm[t * 8 + 6];
            o1.w = f[t * 8 + 7] * rn * cm[t * 8 + 7];
            *reinterpret_cast<float4*>(ob + (size_t)n * M_ + t * 512 + lane * 8) = o0;
            *reinterpret_cast<float4*>(ob + (size_t)n * M_ + t * 512 + lane * 8 + 4) = o1;
        }
    }
}

// ---------------------------------------------------------------------------
extern "C" void kernel_launch(void* const* d_in, const int* in_sizes, int n_in,
                              void* d_out, int out_size, void* d_ws, size_t ws_size,
                              hipStream_t stream) {
    const float* s = (const float*)d_in[0];
    const int* nrows = (const int*)d_in[1];
    const int* ncols = (const int*)d_in[2];
    float* out = (float*)d_out;

    const size_t qbytes = (size_t)B_ * N_ * M_ * sizeof(__half);  // 128 MiB slab (W<=1024 per row)
    __half* q = (__half*)d_ws;                                    // ws proven >= 136 MiB (R5-R16)
    float* pa = (float*)((char*)d_ws + qbytes);                   // 4 MiB
    float* pb = pa + (size_t)B_ * PCHUNK * M_;                    // 4 MiB

    const dim3 blk(256);
    const dim3 g_chunk(PCHUNK, B_);

    prep_pass<<<g_chunk, blk, 0, stream>>>(s, q, pa, nrows, ncols);
    fused_pass_h<<<g_chunk, blk, 0, stream>>>(q, pa, pb, nrows, ncols);  // c0 -> r1 -> p(c2)
    fused_pass_h<<<g_chunk, blk, 0, stream>>>(q, pb, pa, nrows, ncols);  // c2 -> r3 -> p(c4)
    fused_pass_h<<<g_chunk, blk, 0, stream>>>(q, pa, pb, nrows, ncols);  // c4 -> r5 -> p(c6)
    fused_pass_h<<<g_chunk, blk, 0, stream>>>(q, pb, pa, nrows, ncols);  // c6 -> r7 -> p(c8)
    final_pass_h<<<g_chunk, blk, 0, stream>>>(q, pa, out, nrows, ncols); // c8 -> r9 -> out
}